// Round 15
// baseline (204.364 us; speedup 1.0000x reference)
//
#include <hip/hip_runtime.h>
#include <hip/hip_bf16.h>

using bf16 = __hip_bfloat16;
typedef __attribute__((ext_vector_type(8))) short short8;   // 8 bf16 (MFMA A/B frag)
typedef __attribute__((ext_vector_type(4))) short short4v;  // 4 bf16 = b64
typedef __attribute__((ext_vector_type(4))) float f32x4;    // MFMA C/D frag

#define MFMA16(a, b, c) __builtin_amdgcn_mfma_f32_16x16x32_bf16((a), (b), (c), 0, 0, 0)

__device__ inline void async16(bf16* lds, const bf16* g) {
  __builtin_amdgcn_global_load_lds(
      (const __attribute__((address_space(1))) void*)g,
      (__attribute__((address_space(3))) void*)lds, 16, 0, 0);
}

__device__ inline short bfs(float x) {
  union { bf16 h; short s; } u; u.h = __float2bfloat16(x); return u.s;
}
__device__ inline short4v pack4(float a, float b, float c, float d) {
  short4v r; r[0] = bfs(a); r[1] = bfs(b); r[2] = bfs(c); r[3] = bfs(d); return r;
}
// truncating pair pack: {lo16=trunc(x), hi16=trunc(y)} — bias cancels in O=num/den
__device__ inline unsigned pkt2(float x, float y) {
  return __builtin_amdgcn_perm(__float_as_uint(y), __float_as_uint(x), 0x07060302u);
}
// raw HW exp2 (R6-proven: libm exp2f wrapper was >half the VALU budget)
__device__ inline float ex2(float x) {
  float r; asm("v_exp_f32 %0, %1" : "=v"(r) : "v"(x)); return r;
}
// R2-HW-verified semantics: a' = (a_lo32, b_lo32), b' = (a_hi32, b_hi32)
__device__ inline void pl32swap(unsigned& a, unsigned& b) {
  asm("v_permlane32_swap_b32 %0, %1" : "+v"(a), "+v"(b));
}
// 16-lane analog: within each 32-half, a' = (a.q_even, b.q_even), b' = (a.q_odd, b.q_odd)
__device__ inline void pl16swap(unsigned& a, unsigned& b) {
  asm("v_permlane16_swap_b32 %0, %1" : "+v"(a), "+v"(b));
}

// fused fp32->bf16 conversion for x + 4 weight matrices
__global__ __launch_bounds__(256) void cvt_all(
    const float* __restrict__ x,  const float* __restrict__ Wq,
    const float* __restrict__ Wk, const float* __restrict__ Wv,
    const float* __restrict__ Wo,
    bf16* __restrict__ xb, bf16* __restrict__ Wqb, bf16* __restrict__ Wkb,
    bf16* __restrict__ Wvb, bf16* __restrict__ Wob) {
  int i = blockIdx.x * 256 + threadIdx.x;
  const float* s; bf16* d; int off;
  if (i < 1048576)      { s = x;  d = xb;  off = i; }
  else if (i < 1310720) { s = Wq; d = Wqb; off = i - 1048576; }
  else if (i < 1572864) { s = Wk; d = Wkb; off = i - 1310720; }
  else if (i < 1835008) { s = Wv; d = Wvb; off = i - 1572864; }
  else                  { s = Wo; d = Wob; off = i - 1835008; }
  float4 v = ((const float4*)s)[off];
  short4v o = pack4(v.x, v.y, v.z, v.w);
  *(short4v*)&d[(size_t)off * 4] = o;
}

// Fused QKV GEMM -> Q/K [B,H,2048,64], V^T [B,H,64,2048].
// R12-proven: 128x64 tile, grid (32, 48) = 1536 blocks = 6/CU (4 resident,
// LDS 33.8KB) — tile-shrink lever cut 48.3 -> ~42.6us. BK=64, XOR-swizzled
// global_load_lds staging, conflict-free b128 reads. Q pre-scaled by
// 0.125*asc[h]*log2e. V^T epilogue: LDS transpose -> coalesced b64.
__global__ __launch_bounds__(256) void gemm_qkv(
    const bf16* __restrict__ A,
    const bf16* __restrict__ Wq, const bf16* __restrict__ Wk, const bf16* __restrict__ Wv,
    const float* __restrict__ bq, const float* __restrict__ bk, const float* __restrict__ bv,
    const float* __restrict__ asc,
    bf16* __restrict__ Qb, bf16* __restrict__ Kb, bf16* __restrict__ Vtb) {
  __shared__ __align__(16) bf16 As[128 * 64];       // [row][chunk^(row&7)]
  __shared__ __align__(16) bf16 Bs[64 * 64];
  __shared__ __align__(16) bf16 scrT[4][16 * 72];   // V^T transpose scratch

  const int tid = threadIdx.x;
  const int lane = tid & 63;
  const int w = tid >> 6;
  const int m0 = blockIdx.x * 128;
  const int region = blockIdx.y >> 4;               // 3 regions x 16 panels
  const int n0loc = (blockIdx.y & 15) * 64;
  const int wm = (w >> 1) * 64;
  const int wn = (w & 1) * 32;
  const int rq = lane & 15;
  const int quad = lane >> 4;

  const bf16* W = region == 0 ? Wq : (region == 1 ? Wk : Wv);
  const float* bias = region == 0 ? bq : (region == 1 ? bk : bv);
  bf16* C = region == 0 ? Qb : (region == 1 ? Kb : Vtb);

  f32x4 acc[4][2] = {};
  const bf16* Ag = A + (size_t)m0 * 1024;
  const bf16* Wg = W + (size_t)n0loc * 1024;

  const int srow = lane >> 3;                     // 0..7
  const int sws = ((lane & 7) ^ srow) * 8;        // swizzled src chunk offset
  const int c0 = (quad ^ (rq & 7)) * 8;           // frag retrieval (kstep 0)

  for (int k0 = 0; k0 < 1024; k0 += 64) {
    __syncthreads();
#pragma unroll
    for (int t = 0; t < 4; ++t) {                 // A: 128 rows
      int rb = w * 32 + t * 8;
      int row = rb + srow;
      async16(&As[rb * 64 + lane * 8], Ag + (size_t)row * 1024 + k0 + sws);
    }
#pragma unroll
    for (int t = 0; t < 2; ++t) {                 // B: 64 rows
      int rb = w * 16 + t * 8;
      int row = rb + srow;
      async16(&Bs[rb * 64 + lane * 8], Wg + (size_t)row * 1024 + k0 + sws);
    }
    __syncthreads();

#pragma unroll
    for (int ks = 0; ks < 2; ++ks) {
      int off = c0 ^ (ks * 32);
      short8 a[4], b[2];
#pragma unroll
      for (int i = 0; i < 4; ++i) a[i] = *(const short8*)&As[(wm + i * 16 + rq) * 64 + off];
#pragma unroll
      for (int j = 0; j < 2; ++j) b[j] = *(const short8*)&Bs[(wn + j * 16 + rq) * 64 + off];
#pragma unroll
      for (int i = 0; i < 4; ++i)
#pragma unroll
        for (int j = 0; j < 2; ++j) acc[i][j] = MFMA16(a[i], b[j], acc[i][j]);
    }
  }

  const float LOG2E = 1.44269504088896f;
  if (region < 2) {
#pragma unroll
    for (int i = 0; i < 4; ++i)
#pragma unroll
      for (int j = 0; j < 2; ++j)
#pragma unroll
        for (int r2 = 0; r2 < 4; ++r2) {
          int m = m0 + wm + i * 16 + quad * 4 + r2;
          int nr = n0loc + wn + j * 16 + rq;
          int bb = m >> 11, t = m & 2047, h = nr >> 6, hd = nr & 63;
          float v = acc[i][j][r2] + bias[nr];
          if (region == 0) v *= 0.125f * asc[h] * LOG2E;
          C[(((size_t)(bb * 16 + h)) * 2048 + t) * 64 + hd] = __float2bfloat16(v);
        }
  } else {
    // V^T: per-wave transpose -> coalesced b64 stores along t.
    // Block covers ONE head (n0loc 64-aligned); wave covers dims wn..wn+31.
    const int bb = m0 >> 11;
    const int h = n0loc >> 6;
    const int tbase = (m0 & 2047) + wm;
    bf16* scr = scrT[w];
#pragma unroll
    for (int j = 0; j < 2; ++j) {
      int nr = n0loc + wn + j * 16 + rq;
      float bi = bias[nr];
#pragma unroll
      for (int i = 0; i < 4; ++i) {
        short4v pv = pack4(acc[i][j][0] + bi, acc[i][j][1] + bi,
                           acc[i][j][2] + bi, acc[i][j][3] + bi);
        *(short4v*)&scr[rq * 72 + i * 16 + quad * 4] = pv;   // [dim16=rq][t64]
      }
#pragma unroll
      for (int pp = 0; pp < 4; ++pp) {
        int hdl = pp * 4 + quad;
        short4v v4 = *(const short4v*)&scr[hdl * 72 + rq * 4];
        size_t addr = (((size_t)(bb * 16 + h)) * 64 + wn + j * 16 + hdl) * 2048 + tbase + rq * 4;
        *(short4v*)&C[addr] = v4;
      }
    }
  }
}

// Out-proj GEMM + bias + residual (fp32 out). 64x128 tile, grid (64,8) —
// R12-exact (the 201.9us best E2E). R14 A/B: 64x64 was +1.2us vs this;
// R13's "-2.2 credit" for 64x64 was attribution noise. R10 taught: do NOT
// fuse combine here (vmcnt(0) drain at barriers kills the prefetch).
__global__ __launch_bounds__(256) void gemm_out(
    const bf16* __restrict__ A, const bf16* __restrict__ W,
    const float* __restrict__ bias, const float* __restrict__ R,
    float* __restrict__ Y) {
  __shared__ __align__(16) bf16 As[64 * 64];
  __shared__ __align__(16) bf16 Bs[128 * 64];

  const int tid = threadIdx.x;
  const int lane = tid & 63;
  const int w = tid >> 6;
  const int m0 = blockIdx.x * 64;
  const int n0 = blockIdx.y * 128;
  const int wm = (w >> 1) * 32;
  const int wn = (w & 1) * 64;
  const int rq = lane & 15;
  const int quad = lane >> 4;

  f32x4 acc[2][4] = {};
  const bf16* Ag = A + (size_t)m0 * 1024;
  const bf16* Wg = W + (size_t)n0 * 1024;

  const int srow = lane >> 3;
  const int sws = ((lane & 7) ^ srow) * 8;
  const int c0 = (quad ^ (rq & 7)) * 8;

  for (int k0 = 0; k0 < 1024; k0 += 64) {
    __syncthreads();
#pragma unroll
    for (int t = 0; t < 2; ++t) {
      int rb = w * 16 + t * 8;
      int row = rb + srow;
      async16(&As[rb * 64 + lane * 8], Ag + (size_t)row * 1024 + k0 + sws);
    }
#pragma unroll
    for (int t = 0; t < 4; ++t) {
      int rb = w * 32 + t * 8;
      int row = rb + srow;
      async16(&Bs[rb * 64 + lane * 8], Wg + (size_t)row * 1024 + k0 + sws);
    }
    __syncthreads();

#pragma unroll
    for (int ks = 0; ks < 2; ++ks) {
      int off = c0 ^ (ks * 32);
      short8 a[2], b[4];
#pragma unroll
      for (int i = 0; i < 2; ++i) a[i] = *(const short8*)&As[(wm + i * 16 + rq) * 64 + off];
#pragma unroll
      for (int j = 0; j < 4; ++j) b[j] = *(const short8*)&Bs[(wn + j * 16 + rq) * 64 + off];
#pragma unroll
      for (int i = 0; i < 2; ++i)
#pragma unroll
        for (int j = 0; j < 4; ++j) acc[i][j] = MFMA16(a[i], b[j], acc[i][j]);
    }
  }

#pragma unroll
  for (int i = 0; i < 2; ++i)
#pragma unroll
    for (int j = 0; j < 4; ++j)
#pragma unroll
      for (int r2 = 0; r2 < 4; ++r2) {
        int m = m0 + wm + i * 16 + quad * 4 + r2;
        int n = n0 + wn + j * 16 + rq;
        Y[(size_t)m * 1024 + n] = acc[i][j][r2] + bias[n] + R[(size_t)m * 1024 + n];
      }
}

// Flash attention (R12-proven, 42.7us). R13 taught: 8 waves x 16 q-rows
// raises occupancy (27->43%) but REGRESSES (42.7->47): per-wave work per
// barrier interval matters more than resident-wave count. 256 threads /
// 4 waves x 32 q-rows. In-register softmax via swapped 16x16 QK^T, raw
// v_exp, pkt2 pack, permlane 4x4 quad<->reg transpose (no Ps LDS round-trip,
// conflicts = 0). K-split x2 + combine; XCD remap; setprio; single-buffer
// 2-barrier staging (dbuf neutral at 2/3/4 blocks per CU).
__global__ __launch_bounds__(256, 4) void attn_kernel(
    const bf16* __restrict__ Qb, const bf16* __restrict__ Kb,
    const bf16* __restrict__ Vtb,
    bf16* __restrict__ P0, bf16* __restrict__ P1, float* __restrict__ lbuf) {
  __shared__ __align__(16) bf16 Ks[64 * 64];      // [key][chunk^((key>>1)&7)]
  __shared__ __align__(16) bf16 Vs[64 * 64];      // [d][chunk^(d&7)]

  const int wid = blockIdx.x + (blockIdx.y << 4) + (blockIdx.z << 8);
  const int sid = (wid & 7) * 128 + (wid >> 3);
  const int q0 = (sid & 15) * 128;
  const int h = (sid >> 4) & 15;
  const int zz = sid >> 8;
  const int b = zz & 1;
  const int half = zz >> 1;

  const int tid = threadIdx.x;
  const int lane = tid & 63;
  const int w = tid >> 6;
  const int rq = lane & 15;
  const int quad = lane >> 4;

  const size_t head = ((size_t)(b * 16 + h)) * 2048 * 64;
  const bf16* Qh = Qb + head;
  const bf16* Kh = Kb + head;
  const bf16* Vh = Vtb + head;   // [64][2048]

  // Q as B-frag: lane holds Q[q = s*16+rq][d = quad*8..+7 (+32)]
  short8 aq[2][2];
#pragma unroll
  for (int s = 0; s < 2; ++s) {
    const bf16* qrow = Qh + (size_t)(q0 + w * 32 + s * 16 + rq) * 64;
    aq[s][0] = *(const short8*)&qrow[quad * 8];
    aq[s][1] = *(const short8*)&qrow[quad * 8 + 32];
  }

  short8 ones;
#pragma unroll
  for (int i = 0; i < 8; ++i) ones[i] = (short)0x3F80;

  const int srow = lane >> 3;
  const int swsV = ((lane & 7) ^ srow) * 8;            // Vs: g = row&7
  const int c0 = (quad ^ (rq & 7)) * 8;                // bv retrieval
  const int c1 = c0 ^ 32;
  const int kc0 = (quad ^ (rq >> 1)) * 8;              // kA retrieval (g=(row>>1)&7)
  const int kc1 = kc0 ^ 32;

  f32x4 accO[2][4] = {};
  f32x4 lacc[2] = {};

  const int kt0 = half * 16;
  for (int kt = kt0; kt < kt0 + 16; ++kt) {
    __syncthreads();
#pragma unroll
    for (int t = 0; t < 2; ++t) {
      int rb = w * 16 + t * 8;
      int row = rb + srow;
      int swsK = ((lane & 7) ^ ((row >> 1) & 7)) * 8;  // Ks: g=(row>>1)&7
      async16(&Ks[rb * 64 + lane * 8], Kh + (size_t)(kt * 64 + row) * 64 + swsK);
      async16(&Vs[rb * 64 + lane * 8], Vh + (size_t)row * 2048 + kt * 64 + swsV);
    }
    __syncthreads();

    // QK^T swapped: S[s][c] reg r -> key = c*16 + quad*4 + r, q = s*16 + rq
    f32x4 S[2][4] = {};
    __builtin_amdgcn_s_setprio(1);
#pragma unroll
    for (int c = 0; c < 4; ++c) {
      const bf16* kr = &Ks[(c * 16 + rq) * 64];
      short8 k0 = *(const short8*)&kr[kc0];
      short8 k1 = *(const short8*)&kr[kc1];
      S[0][c] = MFMA16(k0, aq[0][0], S[0][c]);
      S[0][c] = MFMA16(k1, aq[0][1], S[0][c]);
      S[1][c] = MFMA16(k0, aq[1][0], S[1][c]);
      S[1][c] = MFMA16(k1, aq[1][1], S[1][c]);
    }
    __builtin_amdgcn_s_setprio(0);

    // exp2 + pack: W[s][c*2+p] = keys c*16 + quad*4 + 2p..2p+1 (bf16 pair)
    unsigned W[2][8];
#pragma unroll
    for (int s = 0; s < 2; ++s)
#pragma unroll
      for (int c = 0; c < 4; ++c) {
        W[s][c * 2 + 0] = pkt2(ex2(S[s][c][0]), ex2(S[s][c][1]));
        W[s][c * 2 + 1] = pkt2(ex2(S[s][c][2]), ex2(S[s][c][3]));
      }

    // 4x4 quad<->reg transpose -> PV A-frags
    short8 ap[2][2];
#pragma unroll
    for (int s = 0; s < 2; ++s) {
      pl32swap(W[s][0], W[s][2]); pl32swap(W[s][1], W[s][3]);
      pl32swap(W[s][4], W[s][6]); pl32swap(W[s][5], W[s][7]);
      pl16swap(W[s][0], W[s][2]); pl16swap(W[s][1], W[s][3]);
      pl16swap(W[s][4], W[s][6]); pl16swap(W[s][5], W[s][7]);
      union { unsigned u[4]; short8 v; } f0, f1;
      f0.u[0] = W[s][0]; f0.u[1] = W[s][1]; f0.u[2] = W[s][2]; f0.u[3] = W[s][3];
      f1.u[0] = W[s][4]; f1.u[1] = W[s][5]; f1.u[2] = W[s][6]; f1.u[3] = W[s][7];
      ap[s][0] = f0.v; ap[s][1] = f1.v;
    }

    // PV + row-sum: bv loaded once, used by both s-tiles
    __builtin_amdgcn_s_setprio(1);
#pragma unroll
    for (int dt = 0; dt < 4; ++dt) {
      const bf16* vr = &Vs[(dt * 16 + rq) * 64];
      short8 v0 = *(const short8*)&vr[c0];
      short8 v1 = *(const short8*)&vr[c1];
      accO[0][dt] = MFMA16(ap[0][0], v0, accO[0][dt]);
      accO[0][dt] = MFMA16(ap[0][1], v1, accO[0][dt]);
      accO[1][dt] = MFMA16(ap[1][0], v0, accO[1][dt]);
      accO[1][dt] = MFMA16(ap[1][1], v1, accO[1][dt]);
    }
#pragma unroll
    for (int s = 0; s < 2; ++s) {
      lacc[s] = MFMA16(ap[s][0], ones, lacc[s]);
      lacc[s] = MFMA16(ap[s][1], ones, lacc[s]);
    }
    __builtin_amdgcn_s_setprio(0);
  }

  bf16* Pout = half ? P1 : P0;
  float* lout = lbuf + half * 65536;
#pragma unroll
  for (int s = 0; s < 2; ++s) {
#pragma unroll
    for (int dt = 0; dt < 4; ++dt)
#pragma unroll
      for (int r = 0; r < 4; ++r) {
        int t = q0 + w * 32 + s * 16 + quad * 4 + r;
        int d = dt * 16 + rq;
        Pout[((size_t)(b * 2048 + t)) * 1024 + h * 64 + d] =
            __float2bfloat16(accO[s][dt][r]);
      }
    if (rq == 0) {
#pragma unroll
      for (int r = 0; r < 4; ++r) {
        int t = q0 + w * 32 + s * 16 + quad * 4 + r;
        lout[(b * 16 + h) * 2048 + t] = lacc[s][r];
      }
    }
  }
}

// Combine K-split partials: attn = (P0 + P1) / (l0 + l1)   (in-place over P0)
__global__ __launch_bounds__(256) void combine_kernel(
    bf16* __restrict__ P0, const bf16* __restrict__ P1,
    const float* __restrict__ lbuf) {
  const int row = blockIdx.x;
  const int tid = threadIdx.x;
  const int col = tid * 4;
  const int b = row >> 11, t = row & 2047;
  const int h = col >> 6;
  const float l = lbuf[(b * 16 + h) * 2048 + t] + lbuf[65536 + (b * 16 + h) * 2048 + t];
  const float rl = 1.f / l;
  size_t base = (size_t)row * 1024 + col;
  short4v p0 = *(const short4v*)&P0[base];
  short4v p1 = *(const short4v*)&P1[base];
  union { short s; bf16 h; } u;
  float v[4];
#pragma unroll
  for (int i = 0; i < 4; ++i) {
    u.s = p0[i]; float a = __bfloat162float(u.h);
    u.s = p1[i]; float c = __bfloat162float(u.h);
    v[i] = (a + c) * rl;
  }
  *(short4v*)&P0[base] = pack4(v[0], v[1], v[2], v[3]);
}

// LayerNorm over D=1024 per row; all fp32
__global__ __launch_bounds__(256) void ln_kernel(
    const float* __restrict__ Y, const float* __restrict__ gamma,
    const float* __restrict__ beta, float* __restrict__ out) {
  const int row = blockIdx.x;
  const int tid = threadIdx.x;
  const int lane = tid & 63;
  const int w = tid >> 6;
  const float* y = Y + (size_t)row * 1024;

  float4 v = *(const float4*)&y[tid * 4];
  float s = v.x + v.y + v.z + v.w;
  float ss = v.x * v.x + v.y * v.y + v.z * v.z + v.w * v.w;
#pragma unroll
  for (int msk = 1; msk < 64; msk <<= 1) {
    s += __shfl_xor(s, msk);
    ss += __shfl_xor(ss, msk);
  }
  __shared__ float red[2][4];
  if (lane == 0) { red[0][w] = s; red[1][w] = ss; }
  __syncthreads();
  s = red[0][0] + red[0][1] + red[0][2] + red[0][3];
  ss = red[1][0] + red[1][1] + red[1][2] + red[1][3];
  float mean = s * (1.f / 1024.f);
  float var = ss * (1.f / 1024.f) - mean * mean;
  float rstd = rsqrtf(var + 1e-5f);
  float4 g = *(const float4*)&gamma[tid * 4];
  float4 bt = *(const float4*)&beta[tid * 4];
  float4 o;
  o.x = (v.x - mean) * rstd * g.x + bt.x;
  o.y = (v.y - mean) * rstd * g.y + bt.y;
  o.z = (v.z - mean) * rstd * g.z + bt.z;
  o.w = (v.w - mean) * rstd * g.w + bt.w;
  *(float4*)&out[(size_t)row * 1024 + tid * 4] = o;
}

extern "C" void kernel_launch(void* const* d_in, const int* in_sizes, int n_in,
                              void* d_out, int out_size, void* d_ws, size_t ws_size,
                              hipStream_t stream) {
  const float* x     = (const float*)d_in[0];
  const float* asc   = (const float*)d_in[1];
  const float* Wq    = (const float*)d_in[2];
  const float* bq    = (const float*)d_in[3];
  const float* Wk    = (const float*)d_in[4];
  const float* bk    = (const float*)d_in[5];
  const float* Wv    = (const float*)d_in[6];
  const float* bv    = (const float*)d_in[7];
  const float* Wo    = (const float*)d_in[8];
  const float* bo    = (const float*)d_in[9];
  const float* gamma = (const float*)d_in[10];
  const float* beta  = (const float*)d_in[11];
  float* out = (float*)d_out;

  char* ws = (char*)d_ws;
  const size_t MB = 1024 * 1024;
  bf16* Qb   = (bf16*)(ws);
  bf16* Kb   = (bf16*)(ws + 8 * MB);
  bf16* Vtb  = (bf16*)(ws + 16 * MB);
  bf16* attn = (bf16*)(ws + 24 * MB);   // P0
  bf16* xb   = (bf16*)(ws + 32 * MB);   // P1 after gemm_qkv
  bf16* Wqb  = (bf16*)(ws + 40 * MB);   // lbuf after gemm_qkv
  bf16* Wkb  = (bf16*)(ws + 42 * MB);
  bf16* Wvb  = (bf16*)(ws + 44 * MB);
  bf16* Wob  = (bf16*)(ws + 46 * MB);
  float* y   = (float*)(ws);            // 16 MiB over dead Qb+Kb
  bf16* P1   = xb;
  float* lbuf = (float*)Wqb;

  cvt_all<<<dim3(8192), dim3(256), 0, stream>>>(x, Wq, Wk, Wv, Wo, xb, Wqb, Wkb, Wvb, Wob);
  gemm_qkv<<<dim3(32, 48), dim3(256), 0, stream>>>(xb, Wqb, Wkb, Wvb, bq, bk, bv, asc, Qb, Kb, Vtb);
  attn_kernel<<<dim3(16, 16, 4), dim3(256), 0, stream>>>(Qb, Kb, Vtb, attn, P1, lbuf);
  combine_kernel<<<dim3(4096), dim3(256), 0, stream>>>(attn, P1, lbuf);
  gemm_out<<<dim3(64, 8), dim3(256), 0, stream>>>(attn, Wob, bo, x, y);
  ln_kernel<<<dim3(4096), dim3(256), 0, stream>>>(y, gamma, beta, out);
}

// Round 16
// 201.471 us; speedup vs baseline: 1.0144x; 1.0144x over previous
//
#include <hip/hip_runtime.h>
#include <hip/hip_bf16.h>

using bf16 = __hip_bfloat16;
typedef __attribute__((ext_vector_type(8))) short short8;   // 8 bf16 (MFMA A/B frag)
typedef __attribute__((ext_vector_type(4))) short short4v;  // 4 bf16 = b64
typedef __attribute__((ext_vector_type(4))) float f32x4;    // MFMA C/D frag

#define MFMA16(a, b, c) __builtin_amdgcn_mfma_f32_16x16x32_bf16((a), (b), (c), 0, 0, 0)

__device__ inline void async16(bf16* lds, const bf16* g) {
  __builtin_amdgcn_global_load_lds(
      (const __attribute__((address_space(1))) void*)g,
      (__attribute__((address_space(3))) void*)lds, 16, 0, 0);
}

__device__ inline short bfs(float x) {
  union { bf16 h; short s; } u; u.h = __float2bfloat16(x); return u.s;
}
__device__ inline short4v pack4(float a, float b, float c, float d) {
  short4v r; r[0] = bfs(a); r[1] = bfs(b); r[2] = bfs(c); r[3] = bfs(d); return r;
}
// truncating pair pack: {lo16=trunc(x), hi16=trunc(y)} — bias cancels in O=num/den
__device__ inline unsigned pkt2(float x, float y) {
  return __builtin_amdgcn_perm(__float_as_uint(y), __float_as_uint(x), 0x07060302u);
}
// raw HW exp2 (R6-proven: libm exp2f wrapper was >half the VALU budget)
__device__ inline float ex2(float x) {
  float r; asm("v_exp_f32 %0, %1" : "=v"(r) : "v"(x)); return r;
}
// R2-HW-verified semantics: a' = (a_lo32, b_lo32), b' = (a_hi32, b_hi32)
__device__ inline void pl32swap(unsigned& a, unsigned& b) {
  asm("v_permlane32_swap_b32 %0, %1" : "+v"(a), "+v"(b));
}
// 16-lane analog: within each 32-half, a' = (a.q_even, b.q_even), b' = (a.q_odd, b.q_odd)
__device__ inline void pl16swap(unsigned& a, unsigned& b) {
  asm("v_permlane16_swap_b32 %0, %1" : "+v"(a), "+v"(b));
}

// fused fp32->bf16 conversion for x + 4 weight matrices
__global__ __launch_bounds__(256) void cvt_all(
    const float* __restrict__ x,  const float* __restrict__ Wq,
    const float* __restrict__ Wk, const float* __restrict__ Wv,
    const float* __restrict__ Wo,
    bf16* __restrict__ xb, bf16* __restrict__ Wqb, bf16* __restrict__ Wkb,
    bf16* __restrict__ Wvb, bf16* __restrict__ Wob) {
  int i = blockIdx.x * 256 + threadIdx.x;
  const float* s; bf16* d; int off;
  if (i < 1048576)      { s = x;  d = xb;  off = i; }
  else if (i < 1310720) { s = Wq; d = Wqb; off = i - 1048576; }
  else if (i < 1572864) { s = Wk; d = Wkb; off = i - 1310720; }
  else if (i < 1835008) { s = Wv; d = Wvb; off = i - 1572864; }
  else                  { s = Wo; d = Wob; off = i - 1835008; }
  float4 v = ((const float4*)s)[off];
  short4v o = pack4(v.x, v.y, v.z, v.w);
  *(short4v*)&d[(size_t)off * 4] = o;
}

// Fused QKV GEMM -> Q/K [B,H,2048,64], V^T [B,H,64,2048].
// R12-proven: 128x64 tile, grid (32, 48) = 1536 blocks = 6/CU (4 resident,
// LDS 33.8KB) — tile-shrink lever cut 48.3 -> ~42.6us. BK=64, XOR-swizzled
// global_load_lds staging, conflict-free b128 reads. Q pre-scaled by
// 0.125*asc[h]*log2e. V^T epilogue: LDS transpose -> coalesced b64.
__global__ __launch_bounds__(256) void gemm_qkv(
    const bf16* __restrict__ A,
    const bf16* __restrict__ Wq, const bf16* __restrict__ Wk, const bf16* __restrict__ Wv,
    const float* __restrict__ bq, const float* __restrict__ bk, const float* __restrict__ bv,
    const float* __restrict__ asc,
    bf16* __restrict__ Qb, bf16* __restrict__ Kb, bf16* __restrict__ Vtb) {
  __shared__ __align__(16) bf16 As[128 * 64];       // [row][chunk^(row&7)]
  __shared__ __align__(16) bf16 Bs[64 * 64];
  __shared__ __align__(16) bf16 scrT[4][16 * 72];   // V^T transpose scratch

  const int tid = threadIdx.x;
  const int lane = tid & 63;
  const int w = tid >> 6;
  const int m0 = blockIdx.x * 128;
  const int region = blockIdx.y >> 4;               // 3 regions x 16 panels
  const int n0loc = (blockIdx.y & 15) * 64;
  const int wm = (w >> 1) * 64;
  const int wn = (w & 1) * 32;
  const int rq = lane & 15;
  const int quad = lane >> 4;

  const bf16* W = region == 0 ? Wq : (region == 1 ? Wk : Wv);
  const float* bias = region == 0 ? bq : (region == 1 ? bk : bv);
  bf16* C = region == 0 ? Qb : (region == 1 ? Kb : Vtb);

  f32x4 acc[4][2] = {};
  const bf16* Ag = A + (size_t)m0 * 1024;
  const bf16* Wg = W + (size_t)n0loc * 1024;

  const int srow = lane >> 3;                     // 0..7
  const int sws = ((lane & 7) ^ srow) * 8;        // swizzled src chunk offset
  const int c0 = (quad ^ (rq & 7)) * 8;           // frag retrieval (kstep 0)

  for (int k0 = 0; k0 < 1024; k0 += 64) {
    __syncthreads();
#pragma unroll
    for (int t = 0; t < 4; ++t) {                 // A: 128 rows
      int rb = w * 32 + t * 8;
      int row = rb + srow;
      async16(&As[rb * 64 + lane * 8], Ag + (size_t)row * 1024 + k0 + sws);
    }
#pragma unroll
    for (int t = 0; t < 2; ++t) {                 // B: 64 rows
      int rb = w * 16 + t * 8;
      int row = rb + srow;
      async16(&Bs[rb * 64 + lane * 8], Wg + (size_t)row * 1024 + k0 + sws);
    }
    __syncthreads();

#pragma unroll
    for (int ks = 0; ks < 2; ++ks) {
      int off = c0 ^ (ks * 32);
      short8 a[4], b[2];
#pragma unroll
      for (int i = 0; i < 4; ++i) a[i] = *(const short8*)&As[(wm + i * 16 + rq) * 64 + off];
#pragma unroll
      for (int j = 0; j < 2; ++j) b[j] = *(const short8*)&Bs[(wn + j * 16 + rq) * 64 + off];
#pragma unroll
      for (int i = 0; i < 4; ++i)
#pragma unroll
        for (int j = 0; j < 2; ++j) acc[i][j] = MFMA16(a[i], b[j], acc[i][j]);
    }
  }

  const float LOG2E = 1.44269504088896f;
  if (region < 2) {
#pragma unroll
    for (int i = 0; i < 4; ++i)
#pragma unroll
      for (int j = 0; j < 2; ++j)
#pragma unroll
        for (int r2 = 0; r2 < 4; ++r2) {
          int m = m0 + wm + i * 16 + quad * 4 + r2;
          int nr = n0loc + wn + j * 16 + rq;
          int bb = m >> 11, t = m & 2047, h = nr >> 6, hd = nr & 63;
          float v = acc[i][j][r2] + bias[nr];
          if (region == 0) v *= 0.125f * asc[h] * LOG2E;
          C[(((size_t)(bb * 16 + h)) * 2048 + t) * 64 + hd] = __float2bfloat16(v);
        }
  } else {
    // V^T: per-wave transpose -> coalesced b64 stores along t.
    // Block covers ONE head (n0loc 64-aligned); wave covers dims wn..wn+31.
    const int bb = m0 >> 11;
    const int h = n0loc >> 6;
    const int tbase = (m0 & 2047) + wm;
    bf16* scr = scrT[w];
#pragma unroll
    for (int j = 0; j < 2; ++j) {
      int nr = n0loc + wn + j * 16 + rq;
      float bi = bias[nr];
#pragma unroll
      for (int i = 0; i < 4; ++i) {
        short4v pv = pack4(acc[i][j][0] + bi, acc[i][j][1] + bi,
                           acc[i][j][2] + bi, acc[i][j][3] + bi);
        *(short4v*)&scr[rq * 72 + i * 16 + quad * 4] = pv;   // [dim16=rq][t64]
      }
#pragma unroll
      for (int pp = 0; pp < 4; ++pp) {
        int hdl = pp * 4 + quad;
        short4v v4 = *(const short4v*)&scr[hdl * 72 + rq * 4];
        size_t addr = (((size_t)(bb * 16 + h)) * 64 + wn + j * 16 + hdl) * 2048 + tbase + rq * 4;
        *(short4v*)&C[addr] = v4;
      }
    }
  }
}

// Out-proj GEMM + bias + residual (fp32 out). 64x128 tile, grid (64,8) —
// R12-exact. R14 A/B: 64x64 was +1.2us vs this. R10: do NOT fuse combine.
__global__ __launch_bounds__(256) void gemm_out(
    const bf16* __restrict__ A, const bf16* __restrict__ W,
    const float* __restrict__ bias, const float* __restrict__ R,
    float* __restrict__ Y) {
  __shared__ __align__(16) bf16 As[64 * 64];
  __shared__ __align__(16) bf16 Bs[128 * 64];

  const int tid = threadIdx.x;
  const int lane = tid & 63;
  const int w = tid >> 6;
  const int m0 = blockIdx.x * 64;
  const int n0 = blockIdx.y * 128;
  const int wm = (w >> 1) * 32;
  const int wn = (w & 1) * 64;
  const int rq = lane & 15;
  const int quad = lane >> 4;

  f32x4 acc[2][4] = {};
  const bf16* Ag = A + (size_t)m0 * 1024;
  const bf16* Wg = W + (size_t)n0 * 1024;

  const int srow = lane >> 3;
  const int sws = ((lane & 7) ^ srow) * 8;
  const int c0 = (quad ^ (rq & 7)) * 8;

  for (int k0 = 0; k0 < 1024; k0 += 64) {
    __syncthreads();
#pragma unroll
    for (int t = 0; t < 2; ++t) {
      int rb = w * 16 + t * 8;
      int row = rb + srow;
      async16(&As[rb * 64 + lane * 8], Ag + (size_t)row * 1024 + k0 + sws);
    }
#pragma unroll
    for (int t = 0; t < 4; ++t) {
      int rb = w * 32 + t * 8;
      int row = rb + srow;
      async16(&Bs[rb * 64 + lane * 8], Wg + (size_t)row * 1024 + k0 + sws);
    }
    __syncthreads();

#pragma unroll
    for (int ks = 0; ks < 2; ++ks) {
      int off = c0 ^ (ks * 32);
      short8 a[2], b[4];
#pragma unroll
      for (int i = 0; i < 2; ++i) a[i] = *(const short8*)&As[(wm + i * 16 + rq) * 64 + off];
#pragma unroll
      for (int j = 0; j < 4; ++j) b[j] = *(const short8*)&Bs[(wn + j * 16 + rq) * 64 + off];
#pragma unroll
      for (int i = 0; i < 2; ++i)
#pragma unroll
        for (int j = 0; j < 4; ++j) acc[i][j] = MFMA16(a[i], b[j], acc[i][j]);
    }
  }

#pragma unroll
  for (int i = 0; i < 2; ++i)
#pragma unroll
    for (int j = 0; j < 4; ++j)
#pragma unroll
      for (int r2 = 0; r2 < 4; ++r2) {
        int m = m0 + wm + i * 16 + quad * 4 + r2;
        int n = n0 + wn + j * 16 + rq;
        Y[(size_t)m * 1024 + n] = acc[i][j][r2] + bias[n] + R[(size_t)m * 1024 + n];
      }
}

// Flash attention R16: KVBLK 64 -> 128 (R13's INVERSE). R13 proved thinner
// work-per-barrier-interval regresses (+10%); this thickens it at constant
// total work: Ks[2][64x64] + Vs[2][64x64] (two halves, each in the proven
// layout/swizzle), 8 outer kt-iterations of 128 keys; ONE barrier-pair
// stages BOTH halves (8 async16/thread, more in-flight per drain), then the
// proven 64-key body runs twice (hf=0,1). Barrier-pairs/block 16 -> 8.
// LDS 32KB (still 4 blocks/CU: 160/32=5, grid-capped 4). VGPR unchanged —
// S/W/ap are per-hf transients. In-register softmax via swapped 16x16 QK^T,
// raw v_exp, pkt2 pack, permlane transpose; K-split x2 + combine; XCD remap;
// setprio.
__global__ __launch_bounds__(256, 4) void attn_kernel(
    const bf16* __restrict__ Qb, const bf16* __restrict__ Kb,
    const bf16* __restrict__ Vtb,
    bf16* __restrict__ P0, bf16* __restrict__ P1, float* __restrict__ lbuf) {
  __shared__ __align__(16) bf16 Ks[2][64 * 64];   // [hf][key][chunk^((key>>1)&7)]
  __shared__ __align__(16) bf16 Vs[2][64 * 64];   // [hf][d][chunk^(d&7)]

  const int wid = blockIdx.x + (blockIdx.y << 4) + (blockIdx.z << 8);
  const int sid = (wid & 7) * 128 + (wid >> 3);
  const int q0 = (sid & 15) * 128;
  const int h = (sid >> 4) & 15;
  const int zz = sid >> 8;
  const int b = zz & 1;
  const int half = zz >> 1;

  const int tid = threadIdx.x;
  const int lane = tid & 63;
  const int w = tid >> 6;
  const int rq = lane & 15;
  const int quad = lane >> 4;

  const size_t head = ((size_t)(b * 16 + h)) * 2048 * 64;
  const bf16* Qh = Qb + head;
  const bf16* Kh = Kb + head;
  const bf16* Vh = Vtb + head;   // [64][2048]

  // Q as B-frag: lane holds Q[q = s*16+rq][d = quad*8..+7 (+32)]
  short8 aq[2][2];
#pragma unroll
  for (int s = 0; s < 2; ++s) {
    const bf16* qrow = Qh + (size_t)(q0 + w * 32 + s * 16 + rq) * 64;
    aq[s][0] = *(const short8*)&qrow[quad * 8];
    aq[s][1] = *(const short8*)&qrow[quad * 8 + 32];
  }

  short8 ones;
#pragma unroll
  for (int i = 0; i < 8; ++i) ones[i] = (short)0x3F80;

  const int srow = lane >> 3;
  const int swsV = ((lane & 7) ^ srow) * 8;            // Vs: g = row&7
  const int c0 = (quad ^ (rq & 7)) * 8;                // bv retrieval
  const int c1 = c0 ^ 32;
  const int kc0 = (quad ^ (rq >> 1)) * 8;              // kA retrieval (g=(row>>1)&7)
  const int kc1 = kc0 ^ 32;

  f32x4 accO[2][4] = {};
  f32x4 lacc[2] = {};

  // 8 tiles of 128 keys; K-split half selects keys [half*1024, half*1024+1024)
  const int kt0 = half * 8;
  for (int kt = kt0; kt < kt0 + 8; ++kt) {
    __syncthreads();
#pragma unroll
    for (int hf = 0; hf < 2; ++hf)
#pragma unroll
      for (int t = 0; t < 2; ++t) {
        int rb = w * 16 + t * 8;
        int row = rb + srow;                             // 0..63 within half
        int swsK = ((lane & 7) ^ ((row >> 1) & 7)) * 8;  // Ks: g=(row>>1)&7
        async16(&Ks[hf][rb * 64 + lane * 8],
                Kh + (size_t)(kt * 128 + hf * 64 + row) * 64 + swsK);
        async16(&Vs[hf][rb * 64 + lane * 8],
                Vh + (size_t)row * 2048 + kt * 128 + hf * 64 + swsV);
      }
    __syncthreads();

#pragma unroll
    for (int hf = 0; hf < 2; ++hf) {
      const bf16* Kc = Ks[hf];
      const bf16* Vc = Vs[hf];

      // QK^T swapped: S[s][c] reg r -> key = c*16 + quad*4 + r, q = s*16+rq
      f32x4 S[2][4] = {};
      __builtin_amdgcn_s_setprio(1);
#pragma unroll
      for (int c = 0; c < 4; ++c) {
        const bf16* kr = &Kc[(c * 16 + rq) * 64];
        short8 k0 = *(const short8*)&kr[kc0];
        short8 k1 = *(const short8*)&kr[kc1];
        S[0][c] = MFMA16(k0, aq[0][0], S[0][c]);
        S[0][c] = MFMA16(k1, aq[0][1], S[0][c]);
        S[1][c] = MFMA16(k0, aq[1][0], S[1][c]);
        S[1][c] = MFMA16(k1, aq[1][1], S[1][c]);
      }
      __builtin_amdgcn_s_setprio(0);

      // exp2 + pack: W[s][c*2+p] = keys c*16 + quad*4 + 2p..2p+1 (bf16 pair)
      unsigned W[2][8];
#pragma unroll
      for (int s = 0; s < 2; ++s)
#pragma unroll
        for (int c = 0; c < 4; ++c) {
          W[s][c * 2 + 0] = pkt2(ex2(S[s][c][0]), ex2(S[s][c][1]));
          W[s][c * 2 + 1] = pkt2(ex2(S[s][c][2]), ex2(S[s][c][3]));
        }

      // 4x4 quad<->reg transpose -> PV A-frags
      short8 ap[2][2];
#pragma unroll
      for (int s = 0; s < 2; ++s) {
        pl32swap(W[s][0], W[s][2]); pl32swap(W[s][1], W[s][3]);
        pl32swap(W[s][4], W[s][6]); pl32swap(W[s][5], W[s][7]);
        pl16swap(W[s][0], W[s][2]); pl16swap(W[s][1], W[s][3]);
        pl16swap(W[s][4], W[s][6]); pl16swap(W[s][5], W[s][7]);
        union { unsigned u[4]; short8 v; } f0, f1;
        f0.u[0] = W[s][0]; f0.u[1] = W[s][1]; f0.u[2] = W[s][2]; f0.u[3] = W[s][3];
        f1.u[0] = W[s][4]; f1.u[1] = W[s][5]; f1.u[2] = W[s][6]; f1.u[3] = W[s][7];
        ap[s][0] = f0.v; ap[s][1] = f1.v;
      }

      // PV + row-sum: bv loaded once, used by both s-tiles
      __builtin_amdgcn_s_setprio(1);
#pragma unroll
      for (int dt = 0; dt < 4; ++dt) {
        const bf16* vr = &Vc[(dt * 16 + rq) * 64];
        short8 v0 = *(const short8*)&vr[c0];
        short8 v1 = *(const short8*)&vr[c1];
        accO[0][dt] = MFMA16(ap[0][0], v0, accO[0][dt]);
        accO[0][dt] = MFMA16(ap[0][1], v1, accO[0][dt]);
        accO[1][dt] = MFMA16(ap[1][0], v0, accO[1][dt]);
        accO[1][dt] = MFMA16(ap[1][1], v1, accO[1][dt]);
      }
#pragma unroll
      for (int s = 0; s < 2; ++s) {
        lacc[s] = MFMA16(ap[s][0], ones, lacc[s]);
        lacc[s] = MFMA16(ap[s][1], ones, lacc[s]);
      }
      __builtin_amdgcn_s_setprio(0);
    }
  }

  bf16* Pout = half ? P1 : P0;
  float* lout = lbuf + half * 65536;
#pragma unroll
  for (int s = 0; s < 2; ++s) {
#pragma unroll
    for (int dt = 0; dt < 4; ++dt)
#pragma unroll
      for (int r = 0; r < 4; ++r) {
        int t = q0 + w * 32 + s * 16 + quad * 4 + r;
        int d = dt * 16 + rq;
        Pout[((size_t)(b * 2048 + t)) * 1024 + h * 64 + d] =
            __float2bfloat16(accO[s][dt][r]);
      }
    if (rq == 0) {
#pragma unroll
      for (int r = 0; r < 4; ++r) {
        int t = q0 + w * 32 + s * 16 + quad * 4 + r;
        lout[(b * 16 + h) * 2048 + t] = lacc[s][r];
      }
    }
  }
}

// Combine K-split partials: attn = (P0 + P1) / (l0 + l1)   (in-place over P0)
__global__ __launch_bounds__(256) void combine_kernel(
    bf16* __restrict__ P0, const bf16* __restrict__ P1,
    const float* __restrict__ lbuf) {
  const int row = blockIdx.x;
  const int tid = threadIdx.x;
  const int col = tid * 4;
  const int b = row >> 11, t = row & 2047;
  const int h = col >> 6;
  const float l = lbuf[(b * 16 + h) * 2048 + t] + lbuf[65536 + (b * 16 + h) * 2048 + t];
  const float rl = 1.f / l;
  size_t base = (size_t)row * 1024 + col;
  short4v p0 = *(const short4v*)&P0[base];
  short4v p1 = *(const short4v*)&P1[base];
  union { short s; bf16 h; } u;
  float v[4];
#pragma unroll
  for (int i = 0; i < 4; ++i) {
    u.s = p0[i]; float a = __bfloat162float(u.h);
    u.s = p1[i]; float c = __bfloat162float(u.h);
    v[i] = (a + c) * rl;
  }
  *(short4v*)&P0[base] = pack4(v[0], v[1], v[2], v[3]);
}

// LayerNorm over D=1024 per row; all fp32
__global__ __launch_bounds__(256) void ln_kernel(
    const float* __restrict__ Y, const float* __restrict__ gamma,
    const float* __restrict__ beta, float* __restrict__ out) {
  const int row = blockIdx.x;
  const int tid = threadIdx.x;
  const int lane = tid & 63;
  const int w = tid >> 6;
  const float* y = Y + (size_t)row * 1024;

  float4 v = *(const float4*)&y[tid * 4];
  float s = v.x + v.y + v.z + v.w;
  float ss = v.x * v.x + v.y * v.y + v.z * v.z + v.w * v.w;
#pragma unroll
  for (int msk = 1; msk < 64; msk <<= 1) {
    s += __shfl_xor(s, msk);
    ss += __shfl_xor(ss, msk);
  }
  __shared__ float red[2][4];
  if (lane == 0) { red[0][w] = s; red[1][w] = ss; }
  __syncthreads();
  s = red[0][0] + red[0][1] + red[0][2] + red[0][3];
  ss = red[1][0] + red[1][1] + red[1][2] + red[1][3];
  float mean = s * (1.f / 1024.f);
  float var = ss * (1.f / 1024.f) - mean * mean;
  float rstd = rsqrtf(var + 1e-5f);
  float4 g = *(const float4*)&gamma[tid * 4];
  float4 bt = *(const float4*)&beta[tid * 4];
  float4 o;
  o.x = (v.x - mean) * rstd * g.x + bt.x;
  o.y = (v.y - mean) * rstd * g.y + bt.y;
  o.z = (v.z - mean) * rstd * g.z + bt.z;
  o.w = (v.w - mean) * rstd * g.w + bt.w;
  *(float4*)&out[(size_t)row * 1024 + tid * 4] = o;
}

extern "C" void kernel_launch(void* const* d_in, const int* in_sizes, int n_in,
                              void* d_out, int out_size, void* d_ws, size_t ws_size,
                              hipStream_t stream) {
  const float* x     = (const float*)d_in[0];
  const float* asc   = (const float*)d_in[1];
  const float* Wq    = (const float*)d_in[2];
  const float* bq    = (const float*)d_in[3];
  const float* Wk    = (const float*)d_in[4];
  const float* bk    = (const float*)d_in[5];
  const float* Wv    = (const float*)d_in[6];
  const float* bv    = (const float*)d_in[7];
  const float* Wo    = (const float*)d_in[8];
  const float* bo    = (const float*)d_in[9];
  const float* gamma = (const float*)d_in[10];
  const float* beta  = (const float*)d_in[11];
  float* out = (float*)d_out;

  char* ws = (char*)d_ws;
  const size_t MB = 1024 * 1024;
  bf16* Qb   = (bf16*)(ws);
  bf16* Kb   = (bf16*)(ws + 8 * MB);
  bf16* Vtb  = (bf16*)(ws + 16 * MB);
  bf16* attn = (bf16*)(ws + 24 * MB);   // P0
  bf16* xb   = (bf16*)(ws + 32 * MB);   // P1 after gemm_qkv
  bf16* Wqb  = (bf16*)(ws + 40 * MB);   // lbuf after gemm_qkv
  bf16* Wkb  = (bf16*)(ws + 42 * MB);
  bf16* Wvb  = (bf16*)(ws + 44 * MB);
  bf16* Wob  = (bf16*)(ws + 46 * MB);
  float* y   = (float*)(ws);            // 16 MiB over dead Qb+Kb
  bf16* P1   = xb;
  float* lbuf = (float*)Wqb;

  cvt_all<<<dim3(8192), dim3(256), 0, stream>>>(x, Wq, Wk, Wv, Wo, xb, Wqb, Wkb, Wvb, Wob);
  gemm_qkv<<<dim3(32, 48), dim3(256), 0, stream>>>(xb, Wqb, Wkb, Wvb, bq, bk, bv, asc, Qb, Kb, Vtb);
  attn_kernel<<<dim3(16, 16, 4), dim3(256), 0, stream>>>(Qb, Kb, Vtb, attn, P1, lbuf);
  combine_kernel<<<dim3(4096), dim3(256), 0, stream>>>(attn, P1, lbuf);
  gemm_out<<<dim3(64, 8), dim3(256), 0, stream>>>(attn, Wob, bo, x, y);
  ln_kernel<<<dim3(4096), dim3(256), 0, stream>>>(y, gamma, beta, out);
}